// Round 7
// baseline (63.942 us; speedup 1.0000x reference)
//
#include <hip/hip_runtime.h>

typedef __attribute__((ext_vector_type(8))) short bf16x8;
typedef __attribute__((ext_vector_type(4))) float f32x4;

__device__ __forceinline__ unsigned short f2bf(float f) {
  unsigned int u = __float_as_uint(f);
  return (unsigned short)((u + 0x7fffu + ((u >> 16) & 1u)) >> 16);  // RNE
}

__device__ __forceinline__ float bf2f(unsigned short s) {
  return __uint_as_float(((unsigned int)s) << 16);
}

__device__ __forceinline__ void gload_lds16(const void* g, void* l) {
  __builtin_amdgcn_global_load_lds((const __attribute__((address_space(1))) void*)g,
                                   (__attribute__((address_space(3))) void*)l,
                                   16, 0, 0);
}

// Cast U, V fp32 -> bf16 (12 MB total traffic, ~2.5us).
__global__ void castUV(const float4* __restrict__ U, const float4* __restrict__ V,
                       ushort4* __restrict__ Ub, ushort4* __restrict__ Vb) {
  const int NU = 256 * 4096 / 4;  // 262144 float4 each
  int i = blockIdx.x * 256 + threadIdx.x;
  const float4* s; ushort4* d; int j;
  if (i < NU) { s = U; d = Ub; j = i; }
  else        { s = V; d = Vb; j = i - NU; }
  float4 v = s[j];
  ushort4 o;
  o.x = f2bf(v.x); o.y = f2bf(v.y); o.z = f2bf(v.z); o.w = f2bf(v.w);
  d[j] = o;
}

// NT GEMM: C[m,n] = sum_k A[m,k]*B[n,k]  (row-major, K contiguous).
// 256 threads = 4 waves (2x2); wave tile (MREP*16) x (NREP*16). BK=32.
// Double-buffered LDS, 1 barrier/K-step. ALL staging via global_load_lds
// (DMA -> latency absorbed at the barrier by all resident waves, no VGPR
// dependency). When AFP32: A is staged as RAW fp32 into LDS and converted
// to bf16 at fragment-read time (16 RNE cvts per frag) — kills the x
// pre-cast pass AND the reg-staged latency chain that plagued rounds 4-6.
// OUT_BF16 selects bf16 C (split-K partials), else fp32 (+bias).
template <int MREP, int NREP, bool BIAS, bool AFP32, bool OUT_BF16>
__global__ __launch_bounds__(256)
void gemm_nt(const void* __restrict__ Ap,
             const unsigned short* __restrict__ B,
             const float* __restrict__ bias,
             void* __restrict__ Cv,
             int lda, int ldb, int ldc,
             int nkt, int kChunk, long long splitStride) {
  constexpr int BM = 32 * MREP;
  constexpr int BN = 32 * NREP;
  constexpr int AELT = AFP32 ? 4 : 2;
  constexpr int ISS_B = BN / 64;

  __shared__ __align__(16) char sA[2][BM * 32 * AELT];
  __shared__ unsigned short sB[2][BN * 32];

  const int tid = threadIdx.x;
  const int l = tid & 63;
  const int w = tid >> 6;
  const int wm = (w >> 1) * (MREP * 16);
  const int wn = (w & 1) * (NREP * 16);
  const int rm = blockIdx.x * BM;
  const int rn = blockIdx.y * BN;
  const int k0base = blockIdx.z * kChunk;

  const int lr = l & 15;         // fragment row (A: M idx, B: N idx)
  const int lc8 = (l >> 4) * 8;  // fragment k offset (contiguous 8 elems)

  auto stage = [&](int kt, int buf) {
    const int k0 = k0base + kt * 32;
#pragma unroll
    for (int is = 0; is < ISS_B; ++is) {
      int eo = is * 2048 + tid * 8;
      gload_lds16(B + (long long)(rn + (eo >> 5)) * ldb + k0 + (eo & 31),
                  &sB[buf][eo]);
    }
    if constexpr (AFP32) {
      const float* A32 = (const float*)Ap;
      // BM*32 floats staged 4/thread/issue (16B)
#pragma unroll
      for (int is = 0; is < BM * 32 / 1024; ++is) {
        int fo = is * 1024 + tid * 4;
        gload_lds16(A32 + (long long)(rm + (fo >> 5)) * lda + k0 + (fo & 31),
                    (float*)sA[buf] + fo);
      }
    } else {
      const unsigned short* A = (const unsigned short*)Ap;
#pragma unroll
      for (int is = 0; is < BM / 64; ++is) {
        int eo = is * 2048 + tid * 8;
        gload_lds16(A + (long long)(rm + (eo >> 5)) * lda + k0 + (eo & 31),
                    (unsigned short*)sA[buf] + eo);
      }
    }
  };

  f32x4 acc[MREP][NREP] = {};

  stage(0, 0);
  for (int kt = 0; kt < nkt; ++kt) {
    __syncthreads();  // drains vmcnt+lgkmcnt: tile kt resident; prev reads done
    if (kt + 1 < nkt) stage(kt + 1, (kt + 1) & 1);
    bf16x8 af[MREP], bfr[NREP];
    if constexpr (AFP32) {
      const float* a0 = (const float*)sA[kt & 1];
#pragma unroll
      for (int m = 0; m < MREP; ++m) {
        const float* p = a0 + (wm + m * 16 + lr) * 32 + lc8;
        float4 u0 = *(const float4*)p;
        float4 u1 = *(const float4*)(p + 4);
        bf16x8 t;
        t[0] = (short)f2bf(u0.x); t[1] = (short)f2bf(u0.y);
        t[2] = (short)f2bf(u0.z); t[3] = (short)f2bf(u0.w);
        t[4] = (short)f2bf(u1.x); t[5] = (short)f2bf(u1.y);
        t[6] = (short)f2bf(u1.z); t[7] = (short)f2bf(u1.w);
        af[m] = t;
      }
    } else {
      const unsigned short* a0 = (const unsigned short*)sA[kt & 1];
#pragma unroll
      for (int m = 0; m < MREP; ++m)
        af[m] = *(const bf16x8*)&a0[(wm + m * 16 + lr) * 32 + lc8];
    }
#pragma unroll
    for (int n = 0; n < NREP; ++n)
      bfr[n] = *(const bf16x8*)&sB[kt & 1][(wn + n * 16 + lr) * 32 + lc8];
#pragma unroll
    for (int m = 0; m < MREP; ++m)
#pragma unroll
      for (int n = 0; n < NREP; ++n)
        acc[m][n] = __builtin_amdgcn_mfma_f32_16x16x32_bf16(af[m], bfr[n], acc[m][n], 0, 0, 0);
  }

  // Epilogue. C/D layout: col = lane&15, row = (lane>>4)*4 + reg.
  const int r0 = rm + wm + (l >> 4) * 4;
  const int c0 = rn + wn + lr;
  if constexpr (OUT_BF16) {
    unsigned short* Cb = (unsigned short*)Cv + (long long)blockIdx.z * splitStride;
#pragma unroll
    for (int n = 0; n < NREP; ++n) {
      const int cc = c0 + n * 16;
#pragma unroll
      for (int m = 0; m < MREP; ++m)
#pragma unroll
        for (int i = 0; i < 4; ++i)
          Cb[(long long)(r0 + m * 16 + i) * ldc + cc] = f2bf(acc[m][n][i]);
    }
  } else {
    float* Cb = (float*)Cv + (long long)blockIdx.z * splitStride;
#pragma unroll
    for (int n = 0; n < NREP; ++n) {
      const int cc = c0 + n * 16;
      const float badd = BIAS ? bias[cc] : 0.0f;
#pragma unroll
      for (int m = 0; m < MREP; ++m)
#pragma unroll
        for (int i = 0; i < 4; ++i)
          Cb[(long long)(r0 + m * 16 + i) * ldc + cc] = acc[m][n][i] + badd;
    }
  }
}

// Sum 16 bf16 split-K partial slices -> bf16 t (fp32 accumulate)
__global__ void reduce16(const ushort4* __restrict__ P, ushort4* __restrict__ t) {
  const int S = 4096 * 256 / 4;  // 262144 ushort4 per slice
  int i = blockIdx.x * 256 + threadIdx.x;
  float sx = 0, sy = 0, sz = 0, sw = 0;
#pragma unroll
  for (int z = 0; z < 16; ++z) {
    ushort4 v = P[i + z * S];
    sx += bf2f(v.x); sy += bf2f(v.y); sz += bf2f(v.z); sw += bf2f(v.w);
  }
  ushort4 o;
  o.x = f2bf(sx); o.y = f2bf(sy); o.z = f2bf(sz); o.w = f2bf(sw);
  t[i] = o;
}

extern "C" void kernel_launch(void* const* d_in, const int* in_sizes, int n_in,
                              void* d_out, int out_size, void* d_ws, size_t ws_size,
                              hipStream_t stream) {
  const float* x    = (const float*)d_in[0];  // [4096,4096]
  const float* U    = (const float*)d_in[1];  // [256,4096]
  const float* V    = (const float*)d_in[2];  // [4096,256]
  const float* bias = (const float*)d_in[3];  // [4096]
  float* out = (float*)d_out;                 // [4096,4096] fp32

  // Workspace layout (38 MB):
  //  [0,32MB)   P: bf16 split-K partials [16][4096][256]
  //  [32,34MB)  t bf16 [4096][256]
  //  [34,36MB)  U bf16 [256][4096]
  //  [36,38MB)  V bf16 [4096][256]
  char* ws = (char*)d_ws;
  unsigned short* P   = (unsigned short*)ws;
  unsigned short* tb  = (unsigned short*)(ws + (32u << 20));
  unsigned short* Ub  = (unsigned short*)(ws + (34u << 20));
  unsigned short* Vb  = (unsigned short*)(ws + (36u << 20));

  castUV<<<2048, 256, 0, stream>>>((const float4*)U, (const float4*)V,
                                   (ushort4*)Ub, (ushort4*)Vb);

  // GEMM1: P[z] = x[:, z*256:(z+1)*256] (fp32 via gload_lds, cvt-on-read)
  //        @ U[:, same]^T  (bf16 out). BM=64, BN=256, grid 64x1x16 = 1024
  //        blocks (3/CU by 48KB LDS), nkt=8.
  dim3 g1(4096 / 64, 1, 16);
  gemm_nt<2, 8, false, true, true><<<g1, 256, 0, stream>>>(
      x, Ub, nullptr, P, 4096, 4096, 256,
      /*nkt=*/8, /*kChunk=*/256, (long long)4096 * 256);

  reduce16<<<(4096 * 256 / 4) / 256, 256, 0, stream>>>((const ushort4*)P, (ushort4*)tb);

  // GEMM2: out = t @ V^T + bias. BM=BN=128, grid 32x32, fp32 out.
  dim3 g2(4096 / 128, 4096 / 128, 1);
  gemm_nt<4, 4, true, false, false><<<g2, 256, 0, stream>>>(
      tb, Vb, bias, out, 256, 256, 4096,
      /*nkt=*/8, /*kChunk=*/0, 0);
}

// Round 8
// 58.866 us; speedup vs baseline: 1.0862x; 1.0862x over previous
//
#include <hip/hip_runtime.h>

typedef __attribute__((ext_vector_type(8))) short bf16x8;
typedef __attribute__((ext_vector_type(4))) float f32x4;

__device__ __forceinline__ unsigned short f2bf(float f) {
  unsigned int u = __float_as_uint(f);
  return (unsigned short)((u + 0x7fffu + ((u >> 16) & 1u)) >> 16);  // RNE
}

__device__ __forceinline__ float bf2f(unsigned short s) {
  return __uint_as_float(((unsigned int)s) << 16);
}

__device__ __forceinline__ void gload_lds16(const void* g, void* l) {
  __builtin_amdgcn_global_load_lds((const __attribute__((address_space(1))) void*)g,
                                   (__attribute__((address_space(3))) void*)l,
                                   16, 0, 0);
}

// prep: (a) gather U into fragment-ordered Upk; (b) cast V -> bf16.
// Upk[((jg*16 + n)*64 + l)*8 + e] = U[n*16 + (l&15)][jg*32 + (l>>4)*8 + e]
// so GEMM1 can stage with linear global_load_lds AND read fragments as
// lane-stride-16B ds_read_b128 (canonical conflict-free pattern).
__global__ void prep(const float* __restrict__ U, const float4* __restrict__ V,
                     unsigned short* __restrict__ Upk, ushort4* __restrict__ Vb) {
  int i = blockIdx.x * 256 + threadIdx.x;
  const int NUP = 128 * 16 * 64;  // 131072 fragment-octets
  if (i < NUP) {
    int l = i & 63, n = (i >> 6) & 15, jg = i >> 10;
    const float* src = U + (long long)(n * 16 + (l & 15)) * 4096 + jg * 32 + (l >> 4) * 8;
    float4 a = *(const float4*)src;
    float4 b = *(const float4*)(src + 4);
    ushort4 o0, o1;
    o0.x = f2bf(a.x); o0.y = f2bf(a.y); o0.z = f2bf(a.z); o0.w = f2bf(a.w);
    o1.x = f2bf(b.x); o1.y = f2bf(b.y); o1.z = f2bf(b.z); o1.w = f2bf(b.w);
    ushort4* d = (ushort4*)(Upk + (long long)i * 8);
    d[0] = o0; d[1] = o1;
  } else {
    int j = i - NUP;  // 262144 float4s of V
    float4 v = V[j];
    ushort4 o;
    o.x = f2bf(v.x); o.y = f2bf(v.y); o.z = f2bf(v.z); o.w = f2bf(v.w);
    Vb[j] = o;
  }
}

// ---------------------------------------------------------------------------
// GEMM1 "U-resident, x-streamed": P[z][m][r] = sum_k x[m, z*256+k]*U[r, z*256+k]
// Grid 16(mg) x 16(z) = 256 blocks = 1/CU. Block: 256 M-rows x 256 N x 256 K.
// One barrier total: stage full U k-chunk (128KB, fragment-ordered) into LDS,
// then a barrier-free K-loop: x streamed global->VGPR one panel ahead (no LDS,
// no vmcnt(0) drains), cvt fp32->bf16 at use, 16 conflict-free ds_read_b128 +
// 16 MFMA per step. 4 panels x 64 rows; 4 waves M-stacked within a panel.
// ---------------------------------------------------------------------------
__global__ __launch_bounds__(256, 1)
void gemm1_ures(const float* __restrict__ x, const unsigned short* __restrict__ Upk,
                unsigned short* __restrict__ P) {
  __shared__ unsigned short sU[8 * 16 * 64 * 8];  // 128 KB

  const int tid = threadIdx.x;
  const int l = tid & 63;
  const int w = tid >> 6;
  const int mg = blockIdx.x;  // M-group: rows [mg*256, mg*256+256)
  const int z  = blockIdx.z;  // K-chunk: cols [z*256, z*256+256)
  const int lr = l & 15;      // row within 16-tile
  const int lg = l >> 4;      // k-octet group

  // Stage U chunk: 65536 bf16 linear from Upk + z*65536.
  {
    const unsigned short* src = Upk + (long long)z * 65536;
#pragma unroll
    for (int is = 0; is < 32; ++is) {
      int eo = is * 2048 + tid * 8;
      gload_lds16(src + eo, &sU[eo]);
    }
  }

  // x stream base: wave w covers rows (mg*256 + p*64 + w*16 + lr).
  const float* xbase = x + (long long)(mg * 256 + w * 16 + lr) * 4096 + z * 256 + lg * 8;

  float4 xr[2][8][2];  // [panel parity][k-step][2x float4] — all static-indexed
#define XLOAD(p, s)                                                     \
  {                                                                     \
    const float* px_ = xbase + (long long)(p) * 64 * 4096;              \
    _Pragma("unroll")                                                   \
    for (int j_ = 0; j_ < 8; ++j_) {                                    \
      xr[s][j_][0] = *(const float4*)(px_ + j_ * 32);                   \
      xr[s][j_][1] = *(const float4*)(px_ + j_ * 32 + 4);               \
    }                                                                   \
  }

  XLOAD(0, 0);
  __syncthreads();  // sU resident (x panel-0 also arrived; harmless)

  unsigned short* Pz = P + (long long)z * (4096LL * 256);

#pragma unroll
  for (int p = 0; p < 4; ++p) {
    if (p < 3) XLOAD(p + 1, (p + 1) & 1);  // prefetch next panel's x
    f32x4 acc[16] = {};
#pragma unroll
    for (int j = 0; j < 8; ++j) {
      float4 u0 = xr[p & 1][j][0], u1 = xr[p & 1][j][1];
      bf16x8 af;
      af[0] = (short)f2bf(u0.x); af[1] = (short)f2bf(u0.y);
      af[2] = (short)f2bf(u0.z); af[3] = (short)f2bf(u0.w);
      af[4] = (short)f2bf(u1.x); af[5] = (short)f2bf(u1.y);
      af[6] = (short)f2bf(u1.z); af[7] = (short)f2bf(u1.w);
#pragma unroll
      for (int n = 0; n < 16; ++n) {
        bf16x8 bfr = *(const bf16x8*)&sU[((j * 16 + n) * 64 + l) * 8];
        acc[n] = __builtin_amdgcn_mfma_f32_16x16x32_bf16(af, bfr, acc[n], 0, 0, 0);
      }
    }
    // Epilogue: C/D layout col = lane&15 (N), row = (lane>>4)*4 + reg (M).
    const int r0 = mg * 256 + p * 64 + w * 16 + lg * 4;
#pragma unroll
    for (int n = 0; n < 16; ++n)
#pragma unroll
      for (int i2 = 0; i2 < 4; ++i2)
        Pz[(long long)(r0 + i2) * 256 + n * 16 + lr] = f2bf(acc[n][i2]);
  }
#undef XLOAD
}

// Sum 16 bf16 split-K partial slices -> bf16 t (fp32 accumulate)
__global__ void reduce16(const ushort4* __restrict__ P, ushort4* __restrict__ t) {
  const int S = 4096 * 256 / 4;  // 262144 ushort4 per slice
  int i = blockIdx.x * 256 + threadIdx.x;
  float sx = 0, sy = 0, sz = 0, sw = 0;
#pragma unroll
  for (int z = 0; z < 16; ++z) {
    ushort4 v = P[i + z * S];
    sx += bf2f(v.x); sy += bf2f(v.y); sz += bf2f(v.z); sw += bf2f(v.w);
  }
  ushort4 o;
  o.x = f2bf(sx); o.y = f2bf(sy); o.z = f2bf(sz); o.w = f2bf(sw);
  t[i] = o;
}

// GEMM2 (proven round-5/6 structure): out = t @ V^T + bias, fp32 out.
// BM=BN=128, BK=32, gload_lds staging, double-buffered, nkt=8.
__global__ __launch_bounds__(256)
void gemm2(const unsigned short* __restrict__ A,
           const unsigned short* __restrict__ B,
           const float* __restrict__ bias,
           float* __restrict__ C) {
  constexpr int MREP = 4, NREP = 4;
  __shared__ unsigned short sA[2][128 * 32];
  __shared__ unsigned short sB[2][128 * 32];

  const int tid = threadIdx.x;
  const int l = tid & 63;
  const int w = tid >> 6;
  const int wm = (w >> 1) * 64;
  const int wn = (w & 1) * 64;
  const int rm = blockIdx.x * 128;
  const int rn = blockIdx.y * 128;
  const int lr = l & 15;
  const int lc8 = (l >> 4) * 8;

  auto stage = [&](int kt, int buf) {
    const int k0 = kt * 32;
#pragma unroll
    for (int is = 0; is < 2; ++is) {
      int eo = is * 2048 + tid * 8;
      gload_lds16(B + (long long)(rn + (eo >> 5)) * 256 + k0 + (eo & 31), &sB[buf][eo]);
    }
#pragma unroll
    for (int is = 0; is < 2; ++is) {
      int eo = is * 2048 + tid * 8;
      gload_lds16(A + (long long)(rm + (eo >> 5)) * 256 + k0 + (eo & 31), &sA[buf][eo]);
    }
  };

  f32x4 acc[MREP][NREP] = {};

  stage(0, 0);
  for (int kt = 0; kt < 8; ++kt) {
    __syncthreads();
    if (kt + 1 < 8) stage(kt + 1, (kt + 1) & 1);
    const unsigned short* a0 = sA[kt & 1];
    const unsigned short* b0 = sB[kt & 1];
    bf16x8 af[MREP], bfr[NREP];
#pragma unroll
    for (int m = 0; m < MREP; ++m)
      af[m] = *(const bf16x8*)&a0[(wm + m * 16 + lr) * 32 + lc8];
#pragma unroll
    for (int n = 0; n < NREP; ++n)
      bfr[n] = *(const bf16x8*)&b0[(wn + n * 16 + lr) * 32 + lc8];
#pragma unroll
    for (int m = 0; m < MREP; ++m)
#pragma unroll
      for (int n = 0; n < NREP; ++n)
        acc[m][n] = __builtin_amdgcn_mfma_f32_16x16x32_bf16(af[m], bfr[n], acc[m][n], 0, 0, 0);
  }

  const int r0 = rm + wm + (l >> 4) * 4;
  const int c0 = rn + wn + lr;
#pragma unroll
  for (int n = 0; n < NREP; ++n) {
    const int cc = c0 + n * 16;
    const float badd = bias[cc];
#pragma unroll
    for (int m = 0; m < MREP; ++m)
#pragma unroll
      for (int i = 0; i < 4; ++i)
        C[(long long)(r0 + m * 16 + i) * 4096 + cc] = acc[m][n][i] + badd;
  }
}

extern "C" void kernel_launch(void* const* d_in, const int* in_sizes, int n_in,
                              void* d_out, int out_size, void* d_ws, size_t ws_size,
                              hipStream_t stream) {
  const float* x    = (const float*)d_in[0];  // [4096,4096]
  const float* U    = (const float*)d_in[1];  // [256,4096]
  const float* V    = (const float*)d_in[2];  // [4096,256]
  const float* bias = (const float*)d_in[3];  // [4096]
  float* out = (float*)d_out;                 // [4096,4096] fp32

  // Workspace (38 MB):
  //  [0,32MB)   P: bf16 split-K partials [16][4096][256]
  //  [32,34MB)  t bf16 [4096][256]
  //  [34,36MB)  Upk bf16 fragment-ordered [128][16][64][8]
  //  [36,38MB)  V bf16 [4096][256]
  char* ws = (char*)d_ws;
  unsigned short* P   = (unsigned short*)ws;
  unsigned short* tb  = (unsigned short*)(ws + (32u << 20));
  unsigned short* Upk = (unsigned short*)(ws + (34u << 20));
  unsigned short* Vb  = (unsigned short*)(ws + (36u << 20));

  prep<<<1536, 256, 0, stream>>>(U, (const float4*)V, Upk, (ushort4*)Vb);

  // GEMM1: grid 16 M-groups x 16 z = 256 blocks (1/CU).
  dim3 g1(16, 1, 16);
  gemm1_ures<<<g1, 256, 0, stream>>>(x, Upk, P);

  reduce16<<<(4096 * 256 / 4) / 256, 256, 0, stream>>>((const ushort4*)P, (ushort4*)tb);

  // GEMM2: out = t @ V^T + bias. grid 32x32.
  dim3 g2(32, 32, 1);
  gemm2<<<g2, 256, 0, stream>>>(tb, Vb, bias, out);
}